// Round 6
// baseline (250.208 us; speedup 1.0000x reference)
//
#include <hip/hip_runtime.h>

// KAN layer forward, MI355X. Inputs AND outputs are float32 buffers.
// Outputs (flat concat, f32): y_out[1024,128], preacts[1024,128,128],
// postacts[1024,128,128], postspline[1024,128,128].
//
// R5 -> R6: R5 was VMEM/DS issue-bound (per wave: 160 loads, 96 scalar
// stores, 96 serial shuffles). Remap: lane = 32*jh + q; lane owns i-quad
// 4q..4q+3 for one j (jh selects which of a j-pair). All big outputs are
// global_store_dwordx4 (1 KB/wave/inst); mask/scales load as dwordx4;
// y_out reduction = 5 shfl_xor over the 32-lane half. Basis hoisted from
// LDS to registers once per wave; inner loop has no LDS traffic.
//
// dur_us includes a ~121 us harness poison fill (788 MB) -- judge the
// kernel as dur_us - 121.

#define IN_DIM  128
#define OUT_DIM 128
#define NUMG    5
#define KORD    3
#define NB      8          // NUMG + KORD basis functions
#define SIZE    (IN_DIM * OUT_DIM)
#define BATCH   1024

__device__ __forceinline__ float dotf(float4 qa, float4 qb, float4 a, float4 b) {
    float r = qa.x * a.x;
    r = fmaf(qa.y, a.y, r); r = fmaf(qa.z, a.z, r); r = fmaf(qa.w, a.w, r);
    r = fmaf(qb.x, b.x, r); r = fmaf(qb.y, b.y, r);
    r = fmaf(qb.z, b.z, r); r = fmaf(qb.w, b.w, r);
    return r;
}

__global__ __launch_bounds__(256) void kan_fused(
    const float* __restrict__ x,
    const float* __restrict__ grid,
    const float* __restrict__ coef,
    const float* __restrict__ scale_base,
    const float* __restrict__ scale_sp,
    const float* __restrict__ mask,
    float* __restrict__ out)
{
    __shared__ float sB[IN_DIM][NB];
    __shared__ float sSilu[IN_DIM];
    __shared__ float sXv[IN_DIM];

    const int tid  = threadIdx.x;
    const int b    = blockIdx.x >> 1;          // batch row
    const int half = blockIdx.x & 1;           // j half: [0,64) or [64,128)

    // ---- Phase 1: basis + silu for i = tid (threads 0..127) ----
    if (tid < IN_DIM) {
        const int i = tid;
        const float xv = x[b * IN_DIM + i];

        float gr[NUMG + 1];
        #pragma unroll
        for (int r = 0; r <= NUMG; ++r) gr[r] = grid[i * (NUMG + 1) + r];

        const float h = (gr[NUMG] - gr[0]) * (1.0f / NUMG);
        float t[NUMG + 1 + 2 * KORD];             // 12 knots
        t[2] = gr[0] - h; t[1] = t[2] - h; t[0] = t[1] - h;
        #pragma unroll
        for (int r = 0; r <= NUMG; ++r) t[KORD + r] = gr[r];
        t[9] = gr[NUMG] + h; t[10] = t[9] + h; t[11] = t[10] + h;

        float B[NUMG + 2 * KORD];                 // 11 -> 10 -> 9 -> 8
        #pragma unroll
        for (int m = 0; m < NUMG + 2 * KORD; ++m)
            B[m] = (xv >= t[m] && xv < t[m + 1]) ? 1.0f : 0.0f;
        #pragma unroll
        for (int p = 1; p <= KORD; ++p) {
            #pragma unroll
            for (int m = 0; m < NUMG + 2 * KORD - p; ++m) {
                B[m] = (xv - t[m]) / (t[m + p] - t[m]) * B[m]
                     + (t[m + p + 1] - xv) / (t[m + p + 1] - t[m + 1]) * B[m + 1];
            }
        }

        #pragma unroll
        for (int m = 0; m < NB; ++m) sB[i][m] = B[m];
        sSilu[i] = xv / (1.0f + __expf(-xv));
        sXv[i]   = xv;
    }
    __syncthreads();

    // ---- Phase 2: lane = 32*jh + q; i-quad = 4q..4q+3; 8 iters x j-pair ----
    const int lane = tid & 63;
    const int w    = tid >> 6;
    const int q    = lane & 31;
    const int jh   = lane >> 5;

    // hoist basis/silu/xv for the 4 i's into registers (one-time LDS reads)
    float4 B0[4], B1[4];
    #pragma unroll
    for (int k = 0; k < 4; ++k) {
        B0[k] = *(const float4*)&sB[4 * q + k][0];
        B1[k] = *(const float4*)&sB[4 * q + k][4];
    }
    const float4 silu4 = *(const float4*)&sSilu[4 * q];
    const float4 xv4   = *(const float4*)&sXv[4 * q];

    float* out_y   = out;
    float* out_pre = out + BATCH * OUT_DIM;
    float* out_act = out_pre + (size_t)BATCH * SIZE;
    float* out_spl = out_act + (size_t)BATCH * SIZE;

    const float4* cp = (const float4*)coef;

    #pragma unroll 2
    for (int it = 0; it < 8; ++it) {
        const int j     = half * 64 + w * 16 + it * 2 + jh;
        const int sbase = j * IN_DIM + 4 * q;

        const float4 mv  = *(const float4*)&mask[sbase];
        const float4 sbv = *(const float4*)&scale_base[sbase];
        const float4 ssv = *(const float4*)&scale_sp[sbase];

        float sp[4], y[4];
        #pragma unroll
        for (int k = 0; k < 4; ++k) {
            const float4 qa = cp[2 * (sbase + k)];
            const float4 qb = cp[2 * (sbase + k) + 1];
            sp[k] = dotf(qa, qb, B0[k], B1[k]);
        }
        y[0] = mv.x * (sbv.x * silu4.x + ssv.x * sp[0]);
        y[1] = mv.y * (sbv.y * silu4.y + ssv.y * sp[1]);
        y[2] = mv.z * (sbv.z * silu4.z + ssv.z * sp[2]);
        y[3] = mv.w * (sbv.w * silu4.w + ssv.w * sp[3]);

        const size_t e = (size_t)b * SIZE + (size_t)sbase;
        *(float4*)&out_pre[e] = xv4;
        *(float4*)&out_act[e] = make_float4(y[0], y[1], y[2], y[3]);
        *(float4*)&out_spl[e] = make_float4(sp[0], sp[1], sp[2], sp[3]);

        float acc = (y[0] + y[1]) + (y[2] + y[3]);
        #pragma unroll
        for (int off = 1; off < 32; off <<= 1)
            acc += __shfl_xor(acc, off, 64);      // stays within the 32-lane half
        if (q == 0) out_y[b * OUT_DIM + j] = acc;
    }
}

extern "C" void kernel_launch(void* const* d_in, const int* in_sizes, int n_in,
                              void* d_out, int out_size, void* d_ws, size_t ws_size,
                              hipStream_t stream)
{
    hipLaunchKernelGGL(kan_fused, dim3(BATCH * 2), dim3(256), 0, stream,
                       (const float*)d_in[0], (const float*)d_in[1],
                       (const float*)d_in[2], (const float*)d_in[3],
                       (const float*)d_in[4], (const float*)d_in[5],
                       (float*)d_out);
}